// Round 20
// baseline (24.159 us; speedup 1.0000x reference)
//
#include <hip/hip_runtime.h>
#include <math.h>

// DMLoss fused kernel for MI355X (gfx950).
// Round 20: R19 retry (compile fix). SMEM-constant scans: segment table and
// ini points read through address_space(4) pointers with wave-uniform
// (readfirstlane'd) addresses -> s_load_dwordx4 into SGPRs; scan DS traffic
// -> 0; VALU (<=1 SGPR operand/inst via rolling-D form) becomes sole binder.
// Fix vs R19: use clang ext_vector float4 (primitive, loads from AS(4) in
// both host+device passes) instead of HIP_vector_type float4.
// Scan arithmetic bit-identical to R16 (best, 17.9us).

#define BB 1024
#define NN 128
#define MM 128

typedef float f4 __attribute__((ext_vector_type(4)));
typedef __attribute__((address_space(4))) const f4* c4p;

__device__ __forceinline__ float sl1(float x) {
    float d = fabsf(x);
    return d < 1.0f ? 0.5f * d * d : d - 0.5f;
}

// ---------------- prep: fused per-batch segment table ----------------
__global__ void __launch_bounds__(128)
dmloss_prep(const float* __restrict__ gt, float* __restrict__ seg)
{
    const int b = blockIdx.x;
    const int m = threadIdx.x;
    __shared__ float2 sg[MM];
    const float2* g2 = (const float2*)(gt + (size_t)b * MM * 2);
    sg[m] = g2[m];
    __syncthreads();
    float2 g = sg[m];
    float2 a = sg[(m + 127) & 127];
    float ex = g.x - a.x, ey = g.y - a.y;
    float A  = ex * ex + ey * ey;
    float inv5 = A > 0.f ? 5.f / A : 0.f;   // degenerate: jv=5, E=0 -> d=Da
    float* o = seg + ((size_t)b * MM + m) * 4;
    o[0] = g.x; o[1] = g.y; o[2] = inv5; o[3] = A * 0.01f;
}

// ---------------- main ----------------
__global__ void __launch_bounds__(256, 8)
dmloss_main(const float* __restrict__ ini, const float* __restrict__ pred,
            const float* __restrict__ gt,  const float* __restrict__ kmask,
            const float* __restrict__ seg, float4* __restrict__ partials)
{
    const int b    = blockIdx.x >> 1;
    const int half = blockIdx.x & 1;      // owns points [64*half, 64*half+64)
    const int tid  = threadIdx.x;
    const int g    = tid & 63;            // owned point: P = 64*half + g
    const int h    = tid >> 6;            // 0..3: scan slice (32 segs / 32 ini)
    const int P    = (half << 6) + g;
    const int hs   = __builtin_amdgcn_readfirstlane(h);   // wave-uniform slice

    __shared__ __align__(16) float2 s_gt[MM];
    __shared__ float2 s_pr[NN];
    __shared__ float  s_step[16];                // exact j/10
    __shared__ float  s_rv[4 * 64];
    __shared__ float  s_rf[4 * 64];
    __shared__ float  s_sum[3][4];

    const float2* gt2 = (const float2*)(gt   + (size_t)b * MM * 2);
    const float2* in2 = (const float2*)(ini  + (size_t)b * NN * 2);
    const float2* pr2 = (const float2*)(pred + (size_t)b * NN * 2);

    // ---- staging (one barrier): gt + pr in LDS for divergent epilogue gathers ----
    if (tid < 128) {
        s_gt[tid] = gt2[tid];
        if (tid < 16) s_step[tid] = (float)tid / 10.0f;
    } else {
        s_pr[tid - 128] = pr2[tid - 128];
    }
    float2 myP = in2[P];                   // ini_pred point (Phase B owner)
    float2 myG = gt2[P];                   // gt point (Phase C owner)
    const float px = myP.x, py = myP.y;

    // Uniform scalar-pipe pointers (inttoptr into constant AS -> s_load).
    c4p segc = (c4p)(uintptr_t)(seg + (size_t)b * MM * 4);
    c4p inic = (c4p)(uintptr_t)(ini + (size_t)b * (NN * 2) + 64 * hs);
    __syncthreads();

    float sumA = 0.f, sumB = 0.f, sumC = 0.f;

    // ---- Phase B: rolling-D scan over segs [32hs, 32hs+32), SMEM constants ----
    // Dg = dist^2(p, gt[m]); jv = (Da-Dg)*inv5 + 5; jr = rint(med3(jv,0,9));
    // d = Da + (E*jr)*(jr - 2*jv); fi = 10*m + jr.  (bit-identical to R16)
    float b0 = INFINITY, f0 = 1e30f;
    {
        const int m0 = 32 * hs;
        f4 Sp = segc[(m0 + 127) & 127];               // s_load (uniform)
        float dax = Sp.x - px, day = Sp.y - py;
        float Da = fmaf(day, day, dax * dax);
        float fm = (float)(320 * hs);
        #pragma unroll 4
        for (int j = 0; j < 32; ++j) {
            f4 S = segc[m0 + j];                      // s_load_dwordx4 (uniform)
            float dgx = S.x - px, dgy = S.y - py;
            float Dg  = fmaf(dgy, dgy, dgx * dgx);
            float jv  = fmaf(Da - Dg, S.z, 5.0f);
            float jr  = rintf(__builtin_amdgcn_fmed3f(jv, 0.f, 9.f));
            float t   = fmaf(jv, -2.f, jr);           // jr - 2*jv
            float d   = fmaf(S.w * jr, t, Da);
            float fi  = fm + jr;
            if (d < b0) { b0 = d; f0 = fi; }          // ascending -> first occ.
            Da = Dg;
            fm += 10.f;
        }
    }
    s_rv[h * 64 + g] = b0;
    s_rf[h * 64 + g] = f0;
    __syncthreads();

    // merge 4 slices (64 active threads) + exact epilogue A
    if (tid < 64) {
        float best = s_rv[tid], bf = s_rf[tid];
        #pragma unroll
        for (int q = 1; q < 4; ++q) {
            float ov = s_rv[q * 64 + tid];
            float of = s_rf[q * 64 + tid];
            if (ov < best || (ov == best && of < bf)) { best = ov; bf = of; }
        }
        int bidx = (int)bf;
        int m = bidx / 10;
        int j = bidx - m * 10;
        float s  = s_step[j];
        float tt = 1.0f - s;
        float2 gm = s_gt[m];
        float2 gp = s_gt[(m + 127) & 127];
        float gx = gm.x * s + gp.x * tt;   // exact reference interp formula
        float gy = gm.y * s + gp.y * tt;
        float2 pr = s_pr[(half << 6) + tid];
        sumA = sl1(pr.x - gx) + sl1(pr.y - gy);
    }
    __syncthreads();   // protect s_rv/s_rf reuse

    // ---- Phase C: owned gt point vs ini slice [32hs, 32hs+32), SMEM pairs ----
    {
        const float gx = myG.x, gy = myG.y;
        float b1 = INFINITY, f1 = 1e30f;
        float fk = (float)(32 * hs);
        #pragma unroll 4
        for (int j = 0; j < 16; ++j) {
            f4 I = inic[j];                           // 2 ini points via s_load
            {
                float dx = I.x - gx, dy = I.y - gy;
                float d  = fmaf(dy, dy, dx * dx);
                if (d < b1) { b1 = d; f1 = fk; }      // index 2j
            }
            {
                float dx = I.z - gx, dy = I.w - gy;
                float d  = fmaf(dy, dy, dx * dx);
                if (d < b1) { b1 = d; f1 = fk + 1.f; }// index 2j+1 (tie keeps x)
            }
            fk += 2.f;
        }
        s_rv[h * 64 + g] = b1;
        s_rf[h * 64 + g] = f1;
    }
    __syncthreads();

    if (tid < 64) {
        float best = s_rv[tid], bf = s_rf[tid];
        #pragma unroll
        for (int q = 1; q < 4; ++q) {
            float ov = s_rv[q * 64 + tid];
            float of = s_rf[q * 64 + tid];
            if (ov < best || (ov == best && of < bf)) { best = ov; bf = of; }
        }
        int k = (int)bf;
        float2 pk2 = s_pr[k];
        float2 g0  = s_gt[(half << 6) + tid];
        float  km  = kmask[b * MM + (half << 6) + tid];
        sumB = km * (sl1(pk2.x - g0.x) + sl1(pk2.y - g0.y));
        sumC = km;
    }

    // ---- Block reduction ----
    #pragma unroll
    for (int off = 32; off > 0; off >>= 1) {
        sumA += __shfl_down(sumA, off);
        sumB += __shfl_down(sumB, off);
        sumC += __shfl_down(sumC, off);
    }
    const int wave = tid >> 6;
    if ((tid & 63) == 0) {
        s_sum[0][wave] = sumA; s_sum[1][wave] = sumB; s_sum[2][wave] = sumC;
    }
    __syncthreads();
    if (tid == 0) {
        float A = 0.f, Bs = 0.f, C = 0.f;
        #pragma unroll
        for (int w = 0; w < 4; ++w) {
            A += s_sum[0][w]; Bs += s_sum[1][w]; C += s_sum[2][w];
        }
        partials[blockIdx.x] = make_float4(A, Bs, C, 0.0f);
    }
}

__global__ void __launch_bounds__(256)
dmloss_final(const float4* __restrict__ partials, float* __restrict__ out)
{
    const int tid = threadIdx.x;
    float A = 0.0f, Bs = 0.0f, C = 0.0f;
    #pragma unroll
    for (int i = tid; i < 2 * BB; i += 256) {
        float4 p = partials[i];
        A += p.x; Bs += p.y; C += p.z;
    }
    #pragma unroll
    for (int off = 32; off > 0; off >>= 1) {
        A  += __shfl_down(A, off);
        Bs += __shfl_down(Bs, off);
        C  += __shfl_down(C, off);
    }
    __shared__ float sA[4], sB[4], sC[4];
    const int wave = tid >> 6, lane = tid & 63;
    if (lane == 0) { sA[wave] = A; sB[wave] = Bs; sC[wave] = C; }
    __syncthreads();
    if (tid == 0) {
        float a  = sA[0] + sA[1] + sA[2] + sA[3];
        float bs = sB[0] + sB[1] + sB[2] + sB[3];
        float c  = sC[0] + sC[1] + sC[2] + sC[3];
        float loss_pred2gt = a / ((float)BB * (float)NN * 2.0f);
        float loss_set2set = bs / (2.0f * c + 1.0f) + loss_pred2gt;
        out[0] = 0.5f * loss_set2set;
    }
}

extern "C" void kernel_launch(void* const* d_in, const int* in_sizes, int n_in,
                              void* d_out, int out_size, void* d_ws, size_t ws_size,
                              hipStream_t stream)
{
    const float* ini   = (const float*)d_in[0];
    const float* pred  = (const float*)d_in[1];
    const float* gt    = (const float*)d_in[2];
    const float* kmask = (const float*)d_in[3];

    float*  seg      = (float*)d_ws;                       // 1024*128*16B = 2 MB
    float4* partials = (float4*)(seg + (size_t)BB * MM * 4); // [2048]

    dmloss_prep<<<dim3(BB), dim3(128), 0, stream>>>(gt, seg);
    dmloss_main<<<dim3(2 * BB), dim3(256), 0, stream>>>(ini, pred, gt, kmask,
                                                        seg, partials);
    dmloss_final<<<dim3(1), dim3(256), 0, stream>>>(partials, (float*)d_out);
}